// Round 5
// baseline (542.206 us; speedup 1.0000x reference)
//
#include <hip/hip_runtime.h>
#include <math.h>

// Pool: c[16][64][256][256] f32 -> pooled[16M] + eta[67M].
// PASSING exactness chain (R2/R4): threefry2x32 partitionable (bits=y0^y1,
// key (0,42)) + XLA-CPU Cephes log + XLA FastTanh + ascending-K FMA gemms.
// R5: pack tileA/tileB into v_pk_* f32 ops (bit-identical per-half rounding),
// rcp-based tanh divide in the margin-guarded fast path, float2 pooled store.

#define NTILES  16777216u
#define NBLOCKS 32768u
#define MARGIN_EPS 2.0e-4f   // ~50x the fast-path error bound

typedef float v2f __attribute__((ext_vector_type(2)));

__device__ __forceinline__ v2f s2(float v) { v2f r = {v, v}; return r; }
#define PKFMA(a, b, c) __builtin_elementwise_fma((a), (b), (c))

__device__ __forceinline__ unsigned rotl32(unsigned x, int r) {
  return (x << r) | (x >> (32 - r));
}

// Threefry-2x32, 20 rounds, key (0,42), counter (0,i). Returns y0^y1. EXACT.
__device__ __forceinline__ unsigned tf_bits(unsigned i) {
  const unsigned k0 = 0u;
  const unsigned k1 = 42u;
  const unsigned k2 = 0x1BD11BDAu ^ 0u ^ 42u;
  unsigned x0 = 0u + k0;
  unsigned x1 = i + k1;
#define TF_ROUND(r) { x0 += x1; x1 = rotl32(x1, (r)); x1 ^= x0; }
  TF_ROUND(13) TF_ROUND(15) TF_ROUND(26) TF_ROUND(6)
  x0 += k1; x1 += k2 + 1u;
  TF_ROUND(17) TF_ROUND(29) TF_ROUND(16) TF_ROUND(24)
  x0 += k2; x1 += k0 + 2u;
  TF_ROUND(13) TF_ROUND(15) TF_ROUND(26) TF_ROUND(6)
  x0 += k0; x1 += k1 + 3u;
  TF_ROUND(17) TF_ROUND(29) TF_ROUND(16) TF_ROUND(24)
  x0 += k1; x1 += k2 + 4u;
  TF_ROUND(13) TF_ROUND(15) TF_ROUND(26) TF_ROUND(6)
  x0 += k2; x1 += k0 + 5u;
#undef TF_ROUND
  return x0 ^ x1;
}

// XLA CPU Cephes f32 log (FMA-contracted). EXACT replica — fallback path only.
__device__ __forceinline__ float xla_logf(float a) {
  unsigned b = __float_as_uint(a);
  int e = (int)(b >> 23) - 126;
  float m = __uint_as_float((b & 0x007fffffu) | 0x3f000000u);
  bool small = m < 0.70710678118654752440f;
  e -= small ? 1 : 0;
  float m1 = m - 1.0f;
  m = small ? (m1 + m) : m1;
  float z = m * m;
  float y = 7.0376836292e-2f;
  y = fmaf(y, m, -1.1514610310e-1f);
  y = fmaf(y, m,  1.1676998740e-1f);
  y = fmaf(y, m, -1.2420140846e-1f);
  y = fmaf(y, m,  1.4249322787e-1f);
  y = fmaf(y, m, -1.6668057665e-1f);
  y = fmaf(y, m,  2.0000714765e-1f);
  y = fmaf(y, m, -2.4999993993e-1f);
  y = fmaf(y, m,  3.3333331174e-1f);
  y = y * m;
  y = y * z;
  float ef = (float)e;
  y = fmaf(ef, -2.12194440e-4f, y);
  y = fmaf(-0.5f, z, y);
  float r = m + y;
  r = fmaf(ef, 0.693359375f, r);
  return r;
}

// XLA EmitFastTanh, IEEE divide. EXACT replica — fallback path only.
__device__ __forceinline__ float xla_tanhf(float x) {
  float ax = fabsf(x);
  float xc = fminf(fmaxf(x, -7.99881172180175781f), 7.99881172180175781f);
  float x2 = xc * xc;
  float num = -2.76076847742355e-16f;
  num = fmaf(x2, num,  2.00018790482477e-13f);
  num = fmaf(x2, num, -8.60467152213735e-11f);
  num = fmaf(x2, num,  5.12229709037114e-08f);
  num = fmaf(x2, num,  1.48572235717979e-05f);
  num = fmaf(x2, num,  6.37261928875436e-04f);
  num = fmaf(x2, num,  4.89352455891786e-03f);
  num = xc * num;
  float den = 1.19825839466702e-06f;
  den = fmaf(x2, den, 1.18534705686654e-04f);
  den = fmaf(x2, den, 2.26843463243900e-03f);
  den = fmaf(x2, den, 4.89352518554385e-03f);
  float r = num / den;
  return (ax < 0.0004f) ? x : r;
}

__device__ __forceinline__ float exact_gumbel(float u) {
  float tl = xla_logf(u);
  return -xla_logf(-tl);
}

// Fast gumbel via v_log_f32 (<=1 ulp). |err| <= ~3e-6 absolute.
__device__ __forceinline__ float fast_gumbel(float u) {
  float lg = __builtin_amdgcn_logf(u);       // log2(u)
  float tn = lg * -0.69314718f;              // -ln(u) > 0
  return __builtin_amdgcn_logf(tn) * -0.69314718f;
}

// Packed FastTanh across two tiles; rcp divide (err ~3e-7, margin-guarded).
__device__ __forceinline__ v2f pk_tanh_fast(v2f x) {
  v2f xc = __builtin_elementwise_min(
             __builtin_elementwise_max(x, s2(-7.99881172180175781f)),
             s2(7.99881172180175781f));
  v2f x2 = xc * xc;
  v2f num = s2(-2.76076847742355e-16f);
  num = PKFMA(x2, num, s2( 2.00018790482477e-13f));
  num = PKFMA(x2, num, s2(-8.60467152213735e-11f));
  num = PKFMA(x2, num, s2( 5.12229709037114e-08f));
  num = PKFMA(x2, num, s2( 1.48572235717979e-05f));
  num = PKFMA(x2, num, s2( 6.37261928875436e-04f));
  num = PKFMA(x2, num, s2( 4.89352455891786e-03f));
  num = xc * num;
  v2f den = s2(1.19825839466702e-06f);
  den = PKFMA(x2, den, s2(1.18534705686654e-04f));
  den = PKFMA(x2, den, s2(2.26843463243900e-03f));
  den = PKFMA(x2, den, s2(4.89352518554385e-03f));
  float rx = num.x * __builtin_amdgcn_rcpf(den.x);
  float ry = num.y * __builtin_amdgcn_rcpf(den.y);
  v2f r;
  r.x = (fabsf(x.x) < 0.0004f) ? x.x : rx;
  r.y = (fabsf(x.y) < 0.0004f) ? x.y : ry;
  return r;
}

// Per-tile sampling: fast gumbel-argmax, exact (R2-chain) fallback on margin.
__device__ __forceinline__ int sample_z(
    unsigned t, float l0, float l1, float l2, float l3,
    float s0, float s1, float s2v, float s3,
    const float* __restrict__ a1, const float* __restrict__ a2) {
  unsigned base = 4u * t;
  float uu[4];
#pragma unroll
  for (int q = 0; q < 4; ++q) {
    unsigned bits = tf_bits(base + (unsigned)q);
    float f = __uint_as_float((bits >> 9) | 0x3f800000u) - 1.0f;
    uu[q] = (f == 0.0f) ? 1.17549435e-38f : f;
  }
  float lf[4] = {l0, l1, l2, l3};
  float best = fast_gumbel(uu[0]) + lf[0];
  float second = -3.402823466e+38f;
  int z = 0;
#pragma unroll
  for (int q = 1; q < 4; ++q) {
    float v = fast_gumbel(uu[q]) + lf[q];
    if (v > best) { second = best; best = v; z = q; }
    else if (v > second) { second = v; }
  }
  if (best - second < MARGIN_EPS) {
    // EXACT replica of the R2 decision chain (IEEE-div tanh + Cephes gumbel)
    float h[4];
#pragma unroll
    for (int q = 0; q < 4; ++q) {
      float acc = a1[q * 4 + 0] * s0;
      acc = fmaf(a1[q * 4 + 1], s1, acc);
      acc = fmaf(a1[q * 4 + 2], s2v, acc);
      acc = fmaf(a1[q * 4 + 3], s3, acc);
      h[q] = xla_tanhf(acc);
    }
    float le[4];
#pragma unroll
    for (int q = 0; q < 4; ++q) {
      float acc = a2[q * 4 + 0] * h[0];
      acc = fmaf(a2[q * 4 + 1], h[1], acc);
      acc = fmaf(a2[q * 4 + 2], h[2], acc);
      acc = fmaf(a2[q * 4 + 3], h[3], acc);
      le[q] = acc;
    }
    float vb = exact_gumbel(uu[0]) + le[0];
    z = 0;
#pragma unroll
    for (int q = 1; q < 4; ++q) {
      float v = exact_gumbel(uu[q]) + le[q];
      if (v > vb) { vb = v; z = q; }
    }
  }
  return z;
}

__global__ __launch_bounds__(256) void pool_sample_kernel(
    const float* __restrict__ c,
    const float* __restrict__ w1,
    const float* __restrict__ w2,
    float* __restrict__ pooled,
    float* __restrict__ eta) {
  unsigned u = blockIdx.x * 256u + threadIdx.x;   // pair id in [0, 8388608)
  unsigned jj = u & 63u;
  unsigned i  = (u >> 6) & 127u;
  unsigned bc = u >> 13;

  float a1[16], a2[16];
#pragma unroll
  for (int k = 0; k < 16; ++k) { a1[k] = w1[k]; a2[k] = w2[k]; }

  size_t off = ((size_t)bc * 256u + 2u * i) * 256u + 4u * jj;
  float4 rA = *reinterpret_cast<const float4*>(c + off);
  float4 rB = *reinterpret_cast<const float4*>(c + off + 256u);

  // pack: .x = tileA, .y = tileB (adjacent tiles)
  v2f t0 = {rA.x, rA.z};
  v2f t1 = {rA.y, rA.w};
  v2f t2 = {rB.x, rB.z};
  v2f t3 = {rB.y, rB.w};

  // h = tanh(W1 . tile): packed ascending-K FMA chain (pk_fma == fma per half)
  v2f h[4];
#pragma unroll
  for (int q = 0; q < 4; ++q) {
    v2f acc = s2(a1[q * 4 + 0]) * t0;
    acc = PKFMA(s2(a1[q * 4 + 1]), t1, acc);
    acc = PKFMA(s2(a1[q * 4 + 2]), t2, acc);
    acc = PKFMA(s2(a1[q * 4 + 3]), t3, acc);
    h[q] = pk_tanh_fast(acc);
  }
  // logits = W2 . h
  v2f l[4];
#pragma unroll
  for (int q = 0; q < 4; ++q) {
    v2f acc = s2(a2[q * 4 + 0]) * h[0];
    acc = PKFMA(s2(a2[q * 4 + 1]), h[1], acc);
    acc = PKFMA(s2(a2[q * 4 + 2]), h[2], acc);
    acc = PKFMA(s2(a2[q * 4 + 3]), h[3], acc);
    l[q] = acc;
  }

  // eta = softmax(logits): |l|<=2, no max-sub; v_exp/v_rcp (loose tolerance)
  v2f e[4];
#pragma unroll
  for (int q = 0; q < 4; ++q) {
    v2f ax = l[q] * s2(1.442695041f);
    e[q].x = __builtin_amdgcn_exp2f(ax.x);
    e[q].y = __builtin_amdgcn_exp2f(ax.y);
  }
  v2f sum = ((e[0] + e[1]) + e[2]) + e[3];
  v2f inv;
  inv.x = __builtin_amdgcn_rcpf(sum.x);
  inv.y = __builtin_amdgcn_rcpf(sum.y);
#pragma unroll
  for (int q = 0; q < 4; ++q) e[q] = e[q] * inv;

  // sampling (tile A = .x, tile B = .y)
  unsigned tA = (bc << 14) | (i << 7) | (jj << 1);
  int zA = sample_z(tA,     l[0].x, l[1].x, l[2].x, l[3].x,
                    rA.x, rA.y, rB.x, rB.y, a1, a2);
  int zB = sample_z(tA + 1, l[0].y, l[1].y, l[2].y, l[3].y,
                    rA.z, rA.w, rB.z, rB.w, a1, a2);

  float pvA = rA.x;
  if (zA == 1) pvA = rA.y;
  if (zA == 2) pvA = rB.x;
  if (zA == 3) pvA = rB.y;
  float pvB = rA.z;
  if (zB == 1) pvB = rA.w;
  if (zB == 2) pvB = rB.z;
  if (zB == 3) pvB = rB.w;

  // stores: one float2 (pooled pair), two float4 (eta, contiguous 32B)
  *reinterpret_cast<float2*>(pooled + tA) = make_float2(pvA, pvB);
  size_t ebase = 4u * (size_t)tA;
  *reinterpret_cast<float4*>(eta + ebase) =
      make_float4(e[0].x, e[1].x, e[2].x, e[3].x);
  *reinterpret_cast<float4*>(eta + ebase + 4) =
      make_float4(e[0].y, e[1].y, e[2].y, e[3].y);
}

extern "C" void kernel_launch(void* const* d_in, const int* in_sizes, int n_in,
                              void* d_out, int out_size, void* d_ws, size_t ws_size,
                              hipStream_t stream) {
  const float* c  = (const float*)d_in[0];
  const float* w1 = (const float*)d_in[1];
  const float* w2 = (const float*)d_in[2];
  float* pooled = (float*)d_out;
  float* eta    = (float*)d_out + (size_t)NTILES;

  pool_sample_kernel<<<dim3(NBLOCKS), dim3(256), 0, stream>>>(c, w1, w2, pooled, eta);
}